// Round 3
// baseline (492.365 us; speedup 1.0000x reference)
//
#include <hip/hip_runtime.h>

// Local2DSum: out[b,v,h,s] = log(sum_c exp(x[b,v,h,c]) * exp(acc[v,h,c,s]))
//                          - log(sum_c exp(acc[v,h,c,s]))
// B=64, V=32, H=32, C=256, S=256. Inputs N(0,1) -> exp safe in fp16.
//
// R6: 2 tiles (v,h) per block, grid 512 (one generation, 2 blocks/CU).
// Cross-tile pipelining kills the phase-locked prologue/epilogue convoys:
// tile1's acc chunk0 is prefetched at tile0 ch7, tile1's x tile is loaded
// into registers early in tile0's epilogue (flying across red/Tsm/log/store),
// then exp'd straight into Asm. ALL barriers are lgkm-only so global
// prefetches are never drained. MFMA core unchanged from R5.

typedef _Float16 f16x8 __attribute__((ext_vector_type(8)));
typedef _Float16 f16x2 __attribute__((ext_vector_type(2)));
typedef float f32x4 __attribute__((ext_vector_type(4)));

constexpr int BPITCH = 40;            // f16 per Bsm col (80 B)
constexpr int BBUF   = 256 * BPITCH;  // f16 per buffer (20480 B)

#define LGKM_BARRIER() asm volatile("s_waitcnt lgkmcnt(0)\n\ts_barrier" ::: "memory")

__global__ __launch_bounds__(512, 4)
void logmm_kernel(const float* __restrict__ x,
                  const float* __restrict__ acc,
                  float* __restrict__ out) {
    // LDS: Asm 32768 | Bsm 2x20480 | red 2048 | inv 1024 = 76800 B
    // Epilogue overlay: Tsm[64][260] f32 = 66560 B over Asm+Bsm (dead then).
    __shared__ __align__(16) unsigned char smem[76800];
    _Float16* Asm = (_Float16*)smem;              // exp(x) f16, swizzled
    _Float16* Bsm = (_Float16*)(smem + 32768);    // exp(acc)^T ping-pong
    float*    Tsm = (float*)smem;                 // epilogue [b 0..63][pitch 260]
    float*    red = (float*)(smem + 73728);       // 512 f32 partial denoms
    float*    inv = red + 512;                    // 256 f32 1/denom

    const int tid = threadIdx.x;          // 0..511
    const int bid = blockIdx.x;           // 0..511 -> tiles 2*bid, 2*bid+1

    const int col   = tid & 255;          // s column this thread stages
    const int khalf = (tid >> 8) * 16;    // k sub-range 0..15 or 16..31

    // stage-A thread mapping (shared by direct and reg-staged variants)
    const int half = tid >> 7;            // 0..3
    const int c2   = (tid & 127) * 2;
    const int ablk = c2 >> 3;

    const int w  = tid >> 6;              // wave -> s-slice base w*32 (0..7)
    const int l  = tid & 63;
    const int ln = l & 15;
    const int q  = l >> 4;

    float  kv[2][16];
    float2 xq[16];

    // ---- tile0: preload acc chunk 0 first (latency hides under stage A) ----
    {
        const float* ab0 = acc + (size_t)(bid * 2) * 65536;
        #pragma unroll
        for (int i = 0; i < 16; ++i)
            kv[0][i] = ab0[(size_t)(khalf + i) * 256 + col];
    }

    // ---- tile0 stage A = exp(x) f16 into LDS, XOR-swizzled 16B blocks ----
    {
        const float* xb0 = x + (size_t)(bid * 2) * 256;
        #pragma unroll
        for (int it = 0; it < 16; ++it) {
            int row = it * 4 + half;
            float2 v = *(const float2*)(xb0 + (size_t)row * 262144 + c2);
            f16x2 pk;
            pk.x = (_Float16)__expf(v.x);
            pk.y = (_Float16)__expf(v.y);
            int pb = ablk ^ (row & 7);
            *(f16x2*)(Asm + row * 256 + pb * 8 + (c2 & 7)) = pk;
        }
    }

    #pragma unroll
    for (int t = 0; t < 2; ++t) {
        const int vh = bid * 2 + t;
        const float* ab = acc + (size_t)vh * 65536;   // [c][s]
        float*       ob = out + (size_t)vh * 256;     // b-stride 262144

        f32x4 accv[4][2];
        #pragma unroll
        for (int mt = 0; mt < 4; ++mt)
            #pragma unroll
            for (int nt = 0; nt < 2; ++nt)
                accv[mt][nt] = (f32x4){0.f, 0.f, 0.f, 0.f};
        float csum = 0.f;

        #pragma unroll
        for (int ch = 0; ch < 8; ++ch) {
            const int cb = ch & 1;        // compile-time (full unroll)
            // prefetch: next chunk, or next tile's chunk0 into kv[0]
            if (ch < 7) {
                const int c0n = (ch + 1) * 32;
                #pragma unroll
                for (int i = 0; i < 16; ++i)
                    kv[cb ^ 1][i] = ab[(size_t)(c0n + khalf + i) * 256 + col];
            } else if (t == 0) {
                const float* abn = ab + 65536;        // tile1 acc
                #pragma unroll
                for (int i = 0; i < 16; ++i)
                    kv[0][i] = abn[(size_t)(khalf + i) * 256 + col];
            }
            // process current chunk -> Bsm[buf]
            _Float16* Bb = Bsm + cb * BBUF;
            #pragma unroll
            for (int g = 0; g < 2; ++g) {
                f16x8 pk;
                #pragma unroll
                for (int i = 0; i < 8; ++i) {
                    float e = __expf(kv[cb][g * 8 + i]);
                    csum += e;
                    pk[i] = (_Float16)e;
                }
                int G  = (khalf >> 3) + g;            // logical k-group 0..3
                int pg = G ^ ((col >> 2) & 3);        // XOR swizzle
                *(f16x8*)(Bb + col * BPITCH + pg * 8) = pk;
            }
            // LDS-only barrier: ds_writes visible, global prefetch NOT drained
            LGKM_BARRIER();
            // ---- MFMA step (K=32) ----
            f16x8 bf[2];
            #pragma unroll
            for (int nt = 0; nt < 2; ++nt) {
                int s  = w * 32 + nt * 16 + ln;
                int pg = q ^ ((s >> 2) & 3);
                bf[nt] = *(const f16x8*)(Bb + s * BPITCH + pg * 8);
            }
            f16x8 af[4];
            const int blk = ch * 4 + q;
            #pragma unroll
            for (int mt = 0; mt < 4; ++mt) {
                int r  = mt * 16 + ln;
                int pb = blk ^ (r & 7);
                af[mt] = *(const f16x8*)(Asm + r * 256 + pb * 8);
            }
            #pragma unroll
            for (int mt = 0; mt < 4; ++mt)
                #pragma unroll
                for (int nt = 0; nt < 2; ++nt)
                    accv[mt][nt] = __builtin_amdgcn_mfma_f32_16x16x32_f16(
                        af[mt], bf[nt], accv[mt][nt], 0, 0, 0);
        }

        // ---- epilogue (lgkm-only barriers: keep prefetches in flight) ----
        LGKM_BARRIER();                    // all MFMA LDS reads done
        red[tid] = csum;
        LGKM_BARRIER();

        // issue tile1's x loads NOW (csum dead): fly across the whole epilogue
        if (t == 0) {
            const float* xbn = x + (size_t)(vh + 1) * 256;
            #pragma unroll
            for (int it = 0; it < 16; ++it) {
                int row = it * 4 + half;
                xq[it] = *(const float2*)(xbn + (size_t)row * 262144 + c2);
            }
        }

        if (tid < 256) inv[tid] = 1.0f / (red[tid] + red[tid + 256]);
        LGKM_BARRIER();

        // stage C-tile * inv_den into Tsm[b][s] (pitch 260)
        #pragma unroll
        for (int nt = 0; nt < 2; ++nt) {
            int sl = w * 32 + nt * 16 + ln;
            float invd = inv[sl];
            #pragma unroll
            for (int mt = 0; mt < 4; ++mt) {
                int b0 = mt * 16 + q * 4;
                f32x4 vv = accv[mt][nt];
                #pragma unroll
                for (int r = 0; r < 4; ++r)
                    Tsm[(b0 + r) * 260 + sl] = vv[r] * invd;
            }
        }
        LGKM_BARRIER();

        // conflict-free b128 reads + 1 KB/wave contiguous float4 stores
        #pragma unroll
        for (int it = 0; it < 8; ++it) {
            int idx = it * 512 + tid;
            int b   = idx >> 6;           // wave-uniform row
            int s4  = (idx & 63) * 4;
            f32x4 tv = *(const f32x4*)(Tsm + b * 260 + s4);
            float4 o;
            o.x = __logf(tv[0]);
            o.y = __logf(tv[1]);
            o.z = __logf(tv[2]);
            o.w = __logf(tv[3]);
            *(float4*)(ob + (size_t)b * 262144 + s4) = o;
        }

        // tile1 stage A from registers (Tsm reads done -> Asm safe to overwrite)
        if (t == 0) {
            LGKM_BARRIER();
            #pragma unroll
            for (int it = 0; it < 16; ++it) {
                int row = it * 4 + half;
                f16x2 pk;
                pk.x = (_Float16)__expf(xq[it].x);
                pk.y = (_Float16)__expf(xq[it].y);
                int pb = ablk ^ (row & 7);
                *(f16x2*)(Asm + row * 256 + pb * 8 + (c2 & 7)) = pk;
            }
            // no extra barrier: every wave's Asm writes precede its first
            // main-loop barrier, which precedes any wave's Asm MFMA reads
        }
    }
}

extern "C" void kernel_launch(void* const* d_in, const int* in_sizes, int n_in,
                              void* d_out, int out_size, void* d_ws, size_t ws_size,
                              hipStream_t stream) {
    const float* x   = (const float*)d_in[0];   // [64,32,32,256]
    const float* acc = (const float*)d_in[1];   // [32,32,256,256]
    float* out = (float*)d_out;                 // [64,32,32,256]
    logmm_kernel<<<dim3(512), dim3(512), 0, stream>>>(x, acc, out);
}

// Round 5
// 481.511 us; speedup vs baseline: 1.0225x; 1.0225x over previous
//
#include <hip/hip_runtime.h>

// Local2DSum: out[b,v,h,s] = log(sum_c exp(x[b,v,h,c]) * exp(acc[v,h,c,s]))
//                          - log(sum_c exp(acc[v,h,c,s]))
// B=64, V=32, H=32, C=256, S=256. Inputs N(0,1) -> exp safe in fp16.
//
// R8 == R7 resubmitted (R7 bench died to a container flake, no counters).
// R7: R6 minus the register-prefetch of tile1's x (that pushed the live set
// past the 128-reg cap -> 150 MB of scratch spills, WRITE_SIZE 218 MB).
// Keeps: grid 512 / 2 tiles per block (one generation), cross-tile acc
// chunk0 prefetch into kv[0] (register-neutral), lgkm-only barriers
// everywhere (global prefetches never drained). Tile1 stage-A loads x
// directly from global like tile0's prologue.

typedef _Float16 f16x8 __attribute__((ext_vector_type(8)));
typedef _Float16 f16x2 __attribute__((ext_vector_type(2)));
typedef float f32x4 __attribute__((ext_vector_type(4)));

constexpr int BPITCH = 40;            // f16 per Bsm col (80 B)
constexpr int BBUF   = 256 * BPITCH;  // f16 per buffer (20480 B)

#define LGKM_BARRIER() asm volatile("s_waitcnt lgkmcnt(0)\n\ts_barrier" ::: "memory")

__global__ __launch_bounds__(512, 4)
void logmm_kernel(const float* __restrict__ x,
                  const float* __restrict__ acc,
                  float* __restrict__ out) {
    // LDS: Asm 32768 | Bsm 2x20480 | red 2048 | inv 1024 = 76800 B
    // Epilogue overlay: Tsm[64][260] f32 = 66560 B over Asm+Bsm (dead then).
    __shared__ __align__(16) unsigned char smem[76800];
    _Float16* Asm = (_Float16*)smem;              // exp(x) f16, swizzled
    _Float16* Bsm = (_Float16*)(smem + 32768);    // exp(acc)^T ping-pong
    float*    Tsm = (float*)smem;                 // epilogue [b 0..63][pitch 260]
    float*    red = (float*)(smem + 73728);       // 512 f32 partial denoms
    float*    inv = red + 512;                    // 256 f32 1/denom

    const int tid = threadIdx.x;          // 0..511
    const int bid = blockIdx.x;           // 0..511 -> tiles 2*bid, 2*bid+1

    const int col   = tid & 255;          // s column this thread stages
    const int khalf = (tid >> 8) * 16;    // k sub-range 0..15 or 16..31

    // stage-A thread mapping
    const int half = tid >> 7;            // 0..3
    const int c2   = (tid & 127) * 2;
    const int ablk = c2 >> 3;

    const int w  = tid >> 6;              // wave -> s-slice base w*32 (0..7)
    const int l  = tid & 63;
    const int ln = l & 15;
    const int q  = l >> 4;

    float kv[2][16];

    // ---- tile0: preload acc chunk 0 first (latency hides under stage A) ----
    {
        const float* ab0 = acc + (size_t)(bid * 2) * 65536;
        #pragma unroll
        for (int i = 0; i < 16; ++i)
            kv[0][i] = ab0[(size_t)(khalf + i) * 256 + col];
    }

    // ---- tile0 stage A = exp(x) f16 into LDS, XOR-swizzled 16B blocks ----
    {
        const float* xb0 = x + (size_t)(bid * 2) * 256;
        #pragma unroll
        for (int it = 0; it < 16; ++it) {
            int row = it * 4 + half;
            float2 v = *(const float2*)(xb0 + (size_t)row * 262144 + c2);
            f16x2 pk;
            pk.x = (_Float16)__expf(v.x);
            pk.y = (_Float16)__expf(v.y);
            int pb = ablk ^ (row & 7);
            *(f16x2*)(Asm + row * 256 + pb * 8 + (c2 & 7)) = pk;
        }
    }

    #pragma unroll
    for (int t = 0; t < 2; ++t) {
        const int vh = bid * 2 + t;
        const float* ab = acc + (size_t)vh * 65536;   // [c][s]
        float*       ob = out + (size_t)vh * 256;     // b-stride 262144

        f32x4 accv[4][2];
        #pragma unroll
        for (int mt = 0; mt < 4; ++mt)
            #pragma unroll
            for (int nt = 0; nt < 2; ++nt)
                accv[mt][nt] = (f32x4){0.f, 0.f, 0.f, 0.f};
        float csum = 0.f;

        #pragma unroll
        for (int ch = 0; ch < 8; ++ch) {
            const int cb = ch & 1;        // compile-time (full unroll)
            // prefetch: next chunk, or next tile's chunk0 into kv[0]
            if (ch < 7) {
                const int c0n = (ch + 1) * 32;
                #pragma unroll
                for (int i = 0; i < 16; ++i)
                    kv[cb ^ 1][i] = ab[(size_t)(c0n + khalf + i) * 256 + col];
            } else if (t == 0) {
                const float* abn = ab + 65536;        // tile1 acc
                #pragma unroll
                for (int i = 0; i < 16; ++i)
                    kv[0][i] = abn[(size_t)(khalf + i) * 256 + col];
            }
            // process current chunk -> Bsm[buf]
            _Float16* Bb = Bsm + cb * BBUF;
            #pragma unroll
            for (int g = 0; g < 2; ++g) {
                f16x8 pk;
                #pragma unroll
                for (int i = 0; i < 8; ++i) {
                    float e = __expf(kv[cb][g * 8 + i]);
                    csum += e;
                    pk[i] = (_Float16)e;
                }
                int G  = (khalf >> 3) + g;            // logical k-group 0..3
                int pg = G ^ ((col >> 2) & 3);        // XOR swizzle
                *(f16x8*)(Bb + col * BPITCH + pg * 8) = pk;
            }
            // LDS-only barrier: ds_writes visible, global prefetch NOT drained
            LGKM_BARRIER();
            // ---- MFMA step (K=32) ----
            f16x8 bf[2];
            #pragma unroll
            for (int nt = 0; nt < 2; ++nt) {
                int s  = w * 32 + nt * 16 + ln;
                int pg = q ^ ((s >> 2) & 3);
                bf[nt] = *(const f16x8*)(Bb + s * BPITCH + pg * 8);
            }
            f16x8 af[4];
            const int blk = ch * 4 + q;
            #pragma unroll
            for (int mt = 0; mt < 4; ++mt) {
                int r  = mt * 16 + ln;
                int pb = blk ^ (r & 7);
                af[mt] = *(const f16x8*)(Asm + r * 256 + pb * 8);
            }
            #pragma unroll
            for (int mt = 0; mt < 4; ++mt)
                #pragma unroll
                for (int nt = 0; nt < 2; ++nt)
                    accv[mt][nt] = __builtin_amdgcn_mfma_f32_16x16x32_f16(
                        af[mt], bf[nt], accv[mt][nt], 0, 0, 0);
        }

        // ---- epilogue (lgkm-only barriers: keep prefetches in flight) ----
        LGKM_BARRIER();                    // all MFMA LDS reads done
        red[tid] = csum;
        LGKM_BARRIER();
        if (tid < 256) inv[tid] = 1.0f / (red[tid] + red[tid + 256]);
        LGKM_BARRIER();

        // stage C-tile * inv_den into Tsm[b][s] (pitch 260)
        #pragma unroll
        for (int nt = 0; nt < 2; ++nt) {
            int sl = w * 32 + nt * 16 + ln;
            float invd = inv[sl];
            #pragma unroll
            for (int mt = 0; mt < 4; ++mt) {
                int b0 = mt * 16 + q * 4;
                f32x4 vv = accv[mt][nt];
                #pragma unroll
                for (int r = 0; r < 4; ++r)
                    Tsm[(b0 + r) * 260 + sl] = vv[r] * invd;
            }
        }
        LGKM_BARRIER();

        // conflict-free b128 reads + 1 KB/wave contiguous float4 stores
        #pragma unroll
        for (int it = 0; it < 8; ++it) {
            int idx = it * 512 + tid;
            int b   = idx >> 6;           // wave-uniform row
            int s4  = (idx & 63) * 4;
            f32x4 tv = *(const f32x4*)(Tsm + b * 260 + s4);
            float4 o;
            o.x = __logf(tv[0]);
            o.y = __logf(tv[1]);
            o.z = __logf(tv[2]);
            o.w = __logf(tv[3]);
            *(float4*)(ob + (size_t)b * 262144 + s4) = o;
        }

        // tile1 stage A: direct from global (Tsm reads done -> Asm writable)
        if (t == 0) {
            LGKM_BARRIER();
            const float* xbn = x + (size_t)(vh + 1) * 256;
            #pragma unroll
            for (int it = 0; it < 16; ++it) {
                int row = it * 4 + half;
                float2 v = *(const float2*)(xbn + (size_t)row * 262144 + c2);
                f16x2 pk;
                pk.x = (_Float16)__expf(v.x);
                pk.y = (_Float16)__expf(v.y);
                int pb = ablk ^ (row & 7);
                *(f16x2*)(Asm + row * 256 + pb * 8 + (c2 & 7)) = pk;
            }
            // no extra barrier: every wave's Asm writes precede its first
            // main-loop barrier, which precedes any wave's Asm MFMA reads
        }
    }
}

extern "C" void kernel_launch(void* const* d_in, const int* in_sizes, int n_in,
                              void* d_out, int out_size, void* d_ws, size_t ws_size,
                              hipStream_t stream) {
    const float* x   = (const float*)d_in[0];   // [64,32,32,256]
    const float* acc = (const float*)d_in[1];   // [32,32,256,256]
    float* out = (float*)d_out;                 // [64,32,32,256]
    logmm_kernel<<<dim3(512), dim3(512), 0, stream>>>(x, acc, out);
}